// Round 15
// baseline (182.064 us; speedup 1.0000x reference)
//
#include <hip/hip_runtime.h>

typedef float f32x4 __attribute__((ext_vector_type(4)));
typedef short s16x8 __attribute__((ext_vector_type(8)));
typedef unsigned short us4 __attribute__((ext_vector_type(4)));

#define MFMA16(a, b, c) __builtin_amdgcn_mfma_f32_16x16x32_bf16(a, b, c, 0, 0, 0)

// async global->LDS DMA, 16B per lane. LDS dest must be wave-uniform base + lane*16.
#define GLOAD_LDS16(gp, lp) __builtin_amdgcn_global_load_lds( \
    (__attribute__((address_space(1))) void*)(gp),            \
    (__attribute__((address_space(3))) void*)(lp), 16, 0, 0)

__device__ __forceinline__ unsigned short f2bf(float f) {
    union { float f; unsigned u; } v; v.f = f;
    unsigned r = v.u + 0x7fffu + ((v.u >> 16) & 1u);   // RNE truncate to bf16
    return (unsigned short)(r >> 16);
}

// ---------------------------------------------------------------------------
// 256x256-tile GEMM core, 8 waves (512 thr), BK=32, depth-2 counted vmcnt.
// R9/R11-VERIFIED (179.7µs best config). Wave w: rows [(w>>2)*128,+128),
// cols [(w&3)*64,+64). + T5 setprio around the MFMA cluster (pure hint).
// ---------------------------------------------------------------------------
__device__ __forceinline__ void gemm_core256(
    const unsigned short* __restrict__ Ab, size_t Astride,
    const unsigned short* __restrict__ Bb, size_t Bstride,
    int K, unsigned short* sh, int t, f32x4 acc[8][4])
{
    const int w = t >> 6, lane = t & 63;
    const int c = lane & 15, quad = lane >> 4;
    const int arow = (w >> 2) * 128;
    const int brow = (w & 3) * 64;
    const int srow = t >> 2;
    const int scol = (t & 3) * 8;

    const unsigned short* ga = Ab + (size_t)srow * Astride + scol;
    const unsigned short* gb = Bb + (size_t)srow * Bstride + scol;
    const int ntil = K >> 5;

#define STAGE256(p, bbuf) do {                                      \
        unsigned short* nb = sh + (bbuf) * 16384;                   \
        int kk = (p) * 32;                                          \
        GLOAD_LDS16(ga + kk,                 nb + t * 8);           \
        GLOAD_LDS16(ga + kk + 128 * Astride, nb + 4096 + t * 8);    \
        GLOAD_LDS16(gb + kk,                 nb + 8192 + t * 8);    \
        GLOAD_LDS16(gb + kk + 128 * Bstride, nb + 12288 + t * 8);   \
    } while (0)

    STAGE256(0, 0);
    STAGE256(1, 1);

    int cur = 0;
    for (int i = 0; i < ntil; i++) {
        if (i + 1 < ntil) asm volatile("s_waitcnt vmcnt(4)" ::: "memory");
        else              asm volatile("s_waitcnt vmcnt(0)" ::: "memory");
        __builtin_amdgcn_s_barrier();
        __builtin_amdgcn_sched_barrier(0);

        const unsigned short* buf = sh + cur * 16384;
        s16x8 af[8], bf[4];
        #pragma unroll
        for (int q = 0; q < 8; q++)
            af[q] = *(const s16x8*)(buf + (arow + q * 16 + c) * 32 + quad * 8);
        #pragma unroll
        for (int q = 0; q < 4; q++)
            bf[q] = *(const s16x8*)(buf + 8192 + (brow + q * 16 + c) * 32 + quad * 8);

        asm volatile("s_waitcnt lgkmcnt(0)" ::: "memory");
        __builtin_amdgcn_sched_barrier(0);

        __builtin_amdgcn_s_setprio(1);             // T5: favor MFMA-entering waves
        #pragma unroll
        for (int mt = 0; mt < 8; mt++)
            #pragma unroll
            for (int nt = 0; nt < 4; nt++)
                acc[mt][nt] = MFMA16(af[mt], bf[nt], acc[mt][nt]);
        __builtin_amdgcn_s_setprio(0);

        __builtin_amdgcn_s_barrier();
        __builtin_amdgcn_sched_barrier(0);

        if (i + 2 < ntil) STAGE256(i + 2, cur);
        cur ^= 1;
    }
#undef STAGE256
}

// ---------------------------------------------------------------------------
// prior: one WAVE per (b,i) row — no LDS, no barriers, no atomics.
// ---------------------------------------------------------------------------
__device__ __forceinline__ void prior_wave(
    const float* __restrict__ x, const float* __restrict__ wsv,
    float* __restrict__ pout, int row, int lane)
{
    const float4* xr = (const float4*)(x + (size_t)row * 512);
    const float4* wr = (const float4*)wsv;
    float4 a0 = xr[lane * 2],     b0 = wr[lane * 2];
    float4 a1 = xr[lane * 2 + 1], b1 = wr[lane * 2 + 1];
    float part = a0.x * b0.x + a0.y * b0.y + a0.z * b0.z + a0.w * b0.w
               + a1.x * b1.x + a1.y * b1.y + a1.z * b1.z + a1.w * b1.w;
    #pragma unroll
    for (int o = 32; o; o >>= 1) part += __shfl_xor(part, o, 64);
    float sigma = part;
    float inv2 = 0.5f / (sigma * sigma);

    int i = row & 2047;
    float g[32];
    float sum = 0.f;
    #pragma unroll
    for (int u = 0; u < 8; u++) {
        #pragma unroll
        for (int v = 0; v < 4; v++) {
            float d = (float)(u * 256 + lane * 4 + v - i);
            float e = __expf(-(d * d) * inv2);
            g[u * 4 + v] = e;
            sum += e;
        }
    }
    #pragma unroll
    for (int o = 32; o; o >>= 1) sum += __shfl_xor(sum, o, 64);
    float inv = 1.0f / sum;

    float4* pr = (float4*)(pout + (size_t)row * 2048);
    #pragma unroll
    for (int u = 0; u < 8; u++) {
        float4 o4 = { g[u * 4] * inv, g[u * 4 + 1] * inv,
                      g[u * 4 + 2] * inv, g[u * 4 + 3] * inv };
        pr[u * 64 + lane] = o4;
    }
}

// ---------------------------------------------------------------------------
// Kernel 1: convert x -> bf16 row-major; W{q,k,v} -> bf16 transposed [n][k]
// via 64x64 LDS-transpose tiles. Grid 4288. (R6-verified, unchanged.)
// ---------------------------------------------------------------------------
__global__ __launch_bounds__(256) void k_convert(
    const float* __restrict__ x, const float* __restrict__ wq,
    const float* __restrict__ wk, const float* __restrict__ wv,
    unsigned short* __restrict__ xbf, unsigned short* __restrict__ wt)
{
    __shared__ __align__(16) unsigned short lt[64][72];   // 64x64 tile, padded

    int bid = blockIdx.x, t = threadIdx.x;
    if (bid < 4096) {
        int gid = bid * 256 + t;
        float4 v = ((const float4*)x)[gid];
        us4 o = { f2bf(v.x), f2bf(v.y), f2bf(v.z), f2bf(v.w) };
        ((us4*)xbf)[gid] = o;
    } else {
        int idx = bid - 4096;
        int w = idx >> 6;                    // 0=q 1=k 2=v
        int tile = idx & 63;
        int tk = tile >> 3, tn = tile & 7;
        const float* src = ((w == 0) ? wq : (w == 1) ? wk : wv)
                         + (size_t)(tk * 64) * 512 + tn * 64;

        int row = t >> 2;
        int c0 = (t & 3) * 16;
        const float4* s = (const float4*)(src + (size_t)row * 512 + c0);
        #pragma unroll
        for (int q = 0; q < 4; q++) {
            float4 v = s[q];
            lt[c0 + q * 4 + 0][row] = f2bf(v.x);
            lt[c0 + q * 4 + 1][row] = f2bf(v.y);
            lt[c0 + q * 4 + 2][row] = f2bf(v.z);
            lt[c0 + q * 4 + 3][row] = f2bf(v.w);
        }
        __syncthreads();

        int n = t >> 2;
        int k0 = (t & 3) * 16;
        s16x8 a = *(const s16x8*)&lt[n][k0];
        s16x8 b = *(const s16x8*)&lt[n][k0 + 8];
        unsigned short* dst = wt + (((size_t)(w * 512 + tn * 64 + n)) << 9)
                                 + tk * 64 + k0;
        *(s16x8*)dst = a;
        *(s16x8*)(dst + 8) = b;
    }
}

// ---------------------------------------------------------------------------
// Kernel 2: QKV projection. Grid 192, 512 thr, 64KB static LDS. XCD-chunked
// swizzle (R11-verified, part of −14µs): XCD x owns 4 m-tiles x 6 n-tiles.
// ---------------------------------------------------------------------------
__global__ __launch_bounds__(512, 2) void k_proj(
    const unsigned short* __restrict__ xbf, const unsigned short* __restrict__ wt,
    unsigned short* __restrict__ qbf, unsigned short* __restrict__ kbf,
    unsigned short* __restrict__ vtbf)
{
    __shared__ __align__(16) unsigned short sh[32768];   // 64KB: 2 x 16384

    int t = threadIdx.x;
    int xcd = blockIdx.x & 7, j = blockIdx.x >> 3;    // j in [0,24)
    int mt_ = xcd * 4 + j / 6, nt_ = j % 6;
    int m0 = mt_ * 256, n0 = nt_ * 256;

    f32x4 acc[8][4] = {};
    gemm_core256(xbf + (size_t)m0 * 512, 512, wt + (size_t)n0 * 512, 512,
                 512, sh, t, acc);

    int w = t >> 6, lane = t & 63, c = lane & 15, quad = lane >> 4;
    int wr = w >> 2, wc = w & 3;
    int sel = nt_ >> 1;                           // 0=q 1=k 2=v

    if (sel < 2) {
        unsigned short* dst = sel ? kbf : qbf;
        int ncol0 = n0 - sel * 512;
        #pragma unroll
        for (int mt = 0; mt < 8; mt++) {
            #pragma unroll
            for (int nt = 0; nt < 4; nt++) {
                int col = ncol0 + wc * 64 + nt * 16 + c;
                #pragma unroll
                for (int r = 0; r < 4; r++) {
                    int rw = m0 + wr * 128 + mt * 16 + quad * 4 + r;
                    dst[(size_t)rw * 512 + col] = f2bf(acc[mt][nt][r]);
                }
            }
        }
    } else {
        #pragma unroll
        for (int mt = 0; mt < 8; mt++) {
            int rw0 = m0 + wr * 128 + mt * 16 + quad * 4;
            int bb = rw0 >> 11, nn = rw0 & 2047;
            #pragma unroll
            for (int nt = 0; nt < 4; nt++) {
                int d = (n0 - 1024) + wc * 64 + nt * 16 + c;
                us4 pk = { f2bf(acc[mt][nt][0]), f2bf(acc[mt][nt][1]),
                           f2bf(acc[mt][nt][2]), f2bf(acc[mt][nt][3]) };
                *(us4*)(vtbf + ((size_t)(bb * 512 + d)) * 2048 + nn) = pk;
            }
        }
    }
}

// ---------------------------------------------------------------------------
// Kernel 3: score. Grid 256, 512 thr, 64KB static LDS. XCD-chunked swizzle
// (R11-verified): XCD x owns (b = x>>1, m-half = x&1) -> Q 1MB + K 2MB in L2.
// ---------------------------------------------------------------------------
__global__ __launch_bounds__(512, 2) void k_score(
    const unsigned short* __restrict__ qbf, const unsigned short* __restrict__ kbf,
    unsigned short* __restrict__ pbf)
{
    __shared__ __align__(16) unsigned short sh[32768];

    int t = threadIdx.x;
    int xcd = blockIdx.x & 7, j = blockIdx.x >> 3;    // j in [0,32)
    int b = xcd >> 1;
    int m0 = ((xcd & 1) * 4 + (j >> 3)) * 256;
    int n0 = (j & 7) * 256;

    f32x4 acc[8][4] = {};
    gemm_core256(qbf + (size_t)(b * 2048 + m0) * 512, 512,
                 kbf + (size_t)(b * 2048 + n0) * 512, 512,
                 512, sh, t, acc);

    int w = t >> 6, lane = t & 63, c = lane & 15, quad = lane >> 4;
    int wr = w >> 2, wc = w & 3;
    const float scale = 0.044194173824159216f;    // 1/sqrt(512)

    #pragma unroll
    for (int mt = 0; mt < 8; mt++) {
        #pragma unroll
        for (int nt = 0; nt < 4; nt++) {
            int col = n0 + wc * 64 + nt * 16 + c;
            #pragma unroll
            for (int r2 = 0; r2 < 4; r2++) {
                int row = m0 + wr * 128 + mt * 16 + quad * 4 + r2;
                pbf[(size_t)(b * 2048 + row) * 2048 + col]
                    = f2bf(__expf(acc[mt][nt][r2] * scale));
            }
        }
    }
}

// ---------------------------------------------------------------------------
// k_out body: O = P @ Vt^T / l. 128x64 tile, BK=64 via PAIRED BK=32 slabs
// (R11-VERIFIED BEST, 179.7µs — R12's BK=32 revert was −2.2µs worse; R13's
// depth-4 single-barrier also worse: keep this). 48KB LDS, vmcnt(6) steady,
// 24 MFMA/barrier-pair/wave + T5 setprio. l via ones-fragment MFMA.
// ---------------------------------------------------------------------------
__device__ __forceinline__ void out_body(
    const unsigned short* __restrict__ pbf, const unsigned short* __restrict__ vtbf,
    float* __restrict__ zout, int b, int m0, int n0, int t,
    unsigned short* sh)
{
    const int wave = t >> 6, lane = t & 63;
    const int c = lane & 15, quad = lane >> 4;
    const int wm = (wave >> 1) * 64, wn = (wave & 1) * 32;
    const int srow = t >> 2;
    const int scol = (t & 3) * 8;

    const unsigned short* ga = pbf + (size_t)(b * 2048 + m0 + srow) * 2048 + scol;
    const unsigned short* gb = vtbf + (size_t)(b * 512 + n0 + srow) * 2048 + scol;

    s16x8 ones;
    #pragma unroll
    for (int i = 0; i < 8; i++) ones[i] = (short)0x3F80;    // bf16 1.0

    f32x4 acc[4][2] = {};
    f32x4 accl[4] = {};

#define STAGEPAIR(p, bbuf) do {                                     \
        unsigned short* nb = sh + (bbuf) * 12288;                   \
        int kk = (p) * 64;                                          \
        GLOAD_LDS16(ga + kk,             nb + t * 8);               \
        GLOAD_LDS16(ga + kk + 64 * 2048, nb + 2048 + t * 8);        \
        GLOAD_LDS16(gb + kk,             nb + 4096 + t * 8);        \
        GLOAD_LDS16(ga + kk + 32,             nb + 6144 + t * 8);   \
        GLOAD_LDS16(ga + kk + 32 + 64 * 2048, nb + 8192 + t * 8);   \
        GLOAD_LDS16(gb + kk + 32,             nb + 10240 + t * 8);  \
    } while (0)

    STAGEPAIR(0, 0);
    STAGEPAIR(1, 1);

    int cur = 0;
    for (int i = 0; i < 32; i++) {
        if (i + 1 < 32) asm volatile("s_waitcnt vmcnt(6)" ::: "memory");
        else            asm volatile("s_waitcnt vmcnt(0)" ::: "memory");
        __builtin_amdgcn_s_barrier();
        __builtin_amdgcn_sched_barrier(0);

        const unsigned short* buf = sh + cur * 12288;
        s16x8 a0[4], b0[2], a1[4], b1[2];
        #pragma unroll
        for (int q = 0; q < 4; q++)
            a0[q] = *(const s16x8*)(buf + (wm + q * 16 + c) * 32 + quad * 8);
        #pragma unroll
        for (int q = 0; q < 2; q++)
            b0[q] = *(const s16x8*)(buf + 4096 + (wn + q * 16 + c) * 32 + quad * 8);
        #pragma unroll
        for (int q = 0; q < 4; q++)
            a1[q] = *(const s16x8*)(buf + 6144 + (wm + q * 16 + c) * 32 + quad * 8);
        #pragma unroll
        for (int q = 0; q < 2; q++)
            b1[q] = *(const s16x8*)(buf + 10240 + (wn + q * 16 + c) * 32 + quad * 8);

        asm volatile("s_waitcnt lgkmcnt(0)" ::: "memory");
        __builtin_amdgcn_sched_barrier(0);

        __builtin_amdgcn_s_setprio(1);
        #pragma unroll
        for (int mt = 0; mt < 4; mt++) {
            #pragma unroll
            for (int nt = 0; nt < 2; nt++)
                acc[mt][nt] = MFMA16(a0[mt], b0[nt], acc[mt][nt]);
            accl[mt] = MFMA16(a0[mt], ones, accl[mt]);
        }
        #pragma unroll
        for (int mt = 0; mt < 4; mt++) {
            #pragma unroll
            for (int nt = 0; nt < 2; nt++)
                acc[mt][nt] = MFMA16(a1[mt], b1[nt], acc[mt][nt]);
            accl[mt] = MFMA16(a1[mt], ones, accl[mt]);
        }
        __builtin_amdgcn_s_setprio(0);

        __builtin_amdgcn_s_barrier();
        __builtin_amdgcn_sched_barrier(0);

        if (i + 2 < 32) STAGEPAIR(i + 2, cur);
        cur ^= 1;
    }
#undef STAGEPAIR

    #pragma unroll
    for (int mt = 0; mt < 4; mt++) {
        #pragma unroll
        for (int r = 0; r < 4; r++) {
            int row = wm + mt * 16 + quad * 4 + r;
            float inv = 1.0f / accl[mt][r];
            #pragma unroll
            for (int nt = 0; nt < 2; nt++) {
                zout[(size_t)(b * 2048 + m0 + row) * 512 + n0 + wn + nt * 16 + c]
                    = acc[mt][nt][r] * inv;
            }
        }
    }
}

// out block-index decode, XCD-chunked (R11-verified, −14µs): XCD x owns
// groups g in [8x, 8x+8) (group = (b,m) pair sharing one 512KB P-tile);
// n fastest -> the 8 sharers of each P-tile are adjacent on ONE XCD's L2.
__device__ __forceinline__ void out_decode(int bid, int& b, int& m0, int& n0)
{
    int xcd = bid & 7, j = bid >> 3;     // j in [0,64)
    int g = xcd * 8 + (j >> 3);          // group in [0,64)
    b = g >> 4;
    m0 = (g & 15) * 128;
    n0 = (j & 7) * 64;
}

// ---------------------------------------------------------------------------
// Kernel 4a (ws path): output + prior merged. Grid 2560 (256 thr):
// [0,512) out tiles (XCD-chunked decode); [512,2560) prior (4 rows/block).
// ---------------------------------------------------------------------------
__global__ __launch_bounds__(256) void k_out_prior(
    const unsigned short* __restrict__ pbf, const unsigned short* __restrict__ vtbf,
    float* __restrict__ zout,
    const float* __restrict__ x, const float* __restrict__ wsv,
    float* __restrict__ pout)
{
    __shared__ __align__(16) unsigned short sh[24576];   // 48KB: 2 x 12288

    int bid = blockIdx.x, t = threadIdx.x;
    if (bid < 512) {
        int b, m0, n0;
        out_decode(bid, b, m0, n0);
        out_body(pbf, vtbf, zout, b, m0, n0, t, sh);
    } else {
        int row = (bid - 512) * 4 + (t >> 6);
        prior_wave(x, wsv, pout, row, t & 63);
    }
}

// ---------------------------------------------------------------------------
// Kernel 4b (fallback): pure output. Grid 512, 256 thr.
// ---------------------------------------------------------------------------
__global__ __launch_bounds__(256) void k_out(
    const unsigned short* __restrict__ pbf, const unsigned short* __restrict__ vtbf,
    float* __restrict__ zout)
{
    __shared__ __align__(16) unsigned short sh[24576];
    int b, m0, n0;
    out_decode(blockIdx.x, b, m0, n0);
    out_body(pbf, vtbf, zout, b, m0, n0, threadIdx.x, sh);
}

// ---------------------------------------------------------------------------
// Kernel 5 (fallback): standalone prior. Grid 2048, 256 thr, 4 rows/block.
// ---------------------------------------------------------------------------
__global__ __launch_bounds__(256) void k_prior(
    const float* __restrict__ x, const float* __restrict__ wsv,
    float* __restrict__ pout)
{
    int row = blockIdx.x * 4 + (threadIdx.x >> 6);
    prior_wave(x, wsv, pout, row, threadIdx.x & 63);
}

// ---------------------------------------------------------------------------
extern "C" void kernel_launch(void* const* d_in, const int* in_sizes, int n_in,
                              void* d_out, int out_size, void* d_ws, size_t ws_size,
                              hipStream_t stream)
{
    const float* x  = (const float*)d_in[0];
    const float* wq = (const float*)d_in[1];
    const float* wk = (const float*)d_in[2];
    const float* wv = (const float*)d_in[3];
    const float* ws = (const float*)d_in[4];

    float* zout = (float*)d_out;                       // (4,2048,512)
    float* pout = zout + (size_t)4 * 2048 * 512;       // (4,2048,2048) = 67.1 MB

    // Scratch: xbf 4.19M + wt 0.79M + q/k/vt 3*4.19M + pbf 16.78M ushorts.
    const size_t need = ((size_t)4194304 + 786432 + 3 * 4194304 + 16777216) * 2;

    if (ws_size >= need) {
        // ---- ws path: all scratch in d_ws; prior overlaps k_out's compute
        unsigned short* base = (unsigned short*)d_ws;
        unsigned short* xbf  = base;
        unsigned short* wt   = xbf  + (size_t)4194304;
        unsigned short* qbf  = wt   + (size_t)786432;
        unsigned short* kbf  = qbf  + (size_t)4194304;
        unsigned short* vtbf = kbf  + (size_t)4194304;
        unsigned short* pbf  = vtbf + (size_t)4194304;

        k_convert  <<<dim3(4288), dim3(256), 0, stream>>>(x, wq, wk, wv, xbf, wt);
        k_proj     <<<dim3(192),  dim3(512), 0, stream>>>(xbf, wt, qbf, kbf, vtbf);
        k_score    <<<dim3(256),  dim3(512), 0, stream>>>(qbf, kbf, pbf);
        k_out_prior<<<dim3(2560), dim3(256), 0, stream>>>(pbf, vtbf, zout, x, ws, pout);
    } else {
        // ---- fallback: scratch inside pout (prior runs last)
        unsigned short* base = (unsigned short*)pout;
        unsigned short* pbf  = base;                        // 16,777,216
        unsigned short* qbf  = base + (size_t)16777216;
        unsigned short* kbf  = qbf  + (size_t)4194304;
        unsigned short* vtbf = kbf  + (size_t)4194304;
        unsigned short* xbf  = base;                        // overlaps pbf (ok)
        unsigned short* wt   = base + (size_t)4194304;      // overlaps pbf (ok)

        k_convert<<<dim3(4288), dim3(256), 0, stream>>>(x, wq, wk, wv, xbf, wt);
        k_proj   <<<dim3(192),  dim3(512), 0, stream>>>(xbf, wt, qbf, kbf, vtbf);
        k_score  <<<dim3(256),  dim3(512), 0, stream>>>(qbf, kbf, pbf);
        k_out    <<<dim3(512),  dim3(256), 0, stream>>>(pbf, vtbf, zout);
        k_prior  <<<dim3(2048), dim3(256), 0, stream>>>(x, ws, pout);
    }
}

// Round 16
// 179.567 us; speedup vs baseline: 1.0139x; 1.0139x over previous
//
#include <hip/hip_runtime.h>

typedef float f32x4 __attribute__((ext_vector_type(4)));
typedef short s16x8 __attribute__((ext_vector_type(8)));
typedef unsigned short us4 __attribute__((ext_vector_type(4)));

#define MFMA16(a, b, c) __builtin_amdgcn_mfma_f32_16x16x32_bf16(a, b, c, 0, 0, 0)

// async global->LDS DMA, 16B per lane. LDS dest must be wave-uniform base + lane*16.
#define GLOAD_LDS16(gp, lp) __builtin_amdgcn_global_load_lds( \
    (__attribute__((address_space(1))) void*)(gp),            \
    (__attribute__((address_space(3))) void*)(lp), 16, 0, 0)

__device__ __forceinline__ unsigned short f2bf(float f) {
    union { float f; unsigned u; } v; v.f = f;
    unsigned r = v.u + 0x7fffu + ((v.u >> 16) & 1u);   // RNE truncate to bf16
    return (unsigned short)(r >> 16);
}

// ---------------------------------------------------------------------------
// 256x256-tile GEMM core, 8 waves (512 thr), BK=32, depth-2 counted vmcnt.
// R9/R11-VERIFIED BEST (179.7µs config; R15 showed +setprio = -2.4µs, so no
// setprio). Wave w: rows [(w>>2)*128,+128), cols [(w&3)*64,+64).
// ---------------------------------------------------------------------------
__device__ __forceinline__ void gemm_core256(
    const unsigned short* __restrict__ Ab, size_t Astride,
    const unsigned short* __restrict__ Bb, size_t Bstride,
    int K, unsigned short* sh, int t, f32x4 acc[8][4])
{
    const int w = t >> 6, lane = t & 63;
    const int c = lane & 15, quad = lane >> 4;
    const int arow = (w >> 2) * 128;
    const int brow = (w & 3) * 64;
    const int srow = t >> 2;
    const int scol = (t & 3) * 8;

    const unsigned short* ga = Ab + (size_t)srow * Astride + scol;
    const unsigned short* gb = Bb + (size_t)srow * Bstride + scol;
    const int ntil = K >> 5;

#define STAGE256(p, bbuf) do {                                      \
        unsigned short* nb = sh + (bbuf) * 16384;                   \
        int kk = (p) * 32;                                          \
        GLOAD_LDS16(ga + kk,                 nb + t * 8);           \
        GLOAD_LDS16(ga + kk + 128 * Astride, nb + 4096 + t * 8);    \
        GLOAD_LDS16(gb + kk,                 nb + 8192 + t * 8);    \
        GLOAD_LDS16(gb + kk + 128 * Bstride, nb + 12288 + t * 8);   \
    } while (0)

    STAGE256(0, 0);
    STAGE256(1, 1);

    int cur = 0;
    for (int i = 0; i < ntil; i++) {
        if (i + 1 < ntil) asm volatile("s_waitcnt vmcnt(4)" ::: "memory");
        else              asm volatile("s_waitcnt vmcnt(0)" ::: "memory");
        __builtin_amdgcn_s_barrier();
        __builtin_amdgcn_sched_barrier(0);

        const unsigned short* buf = sh + cur * 16384;
        s16x8 af[8], bf[4];
        #pragma unroll
        for (int q = 0; q < 8; q++)
            af[q] = *(const s16x8*)(buf + (arow + q * 16 + c) * 32 + quad * 8);
        #pragma unroll
        for (int q = 0; q < 4; q++)
            bf[q] = *(const s16x8*)(buf + 8192 + (brow + q * 16 + c) * 32 + quad * 8);

        asm volatile("s_waitcnt lgkmcnt(0)" ::: "memory");
        __builtin_amdgcn_sched_barrier(0);

        #pragma unroll
        for (int mt = 0; mt < 8; mt++)
            #pragma unroll
            for (int nt = 0; nt < 4; nt++)
                acc[mt][nt] = MFMA16(af[mt], bf[nt], acc[mt][nt]);

        __builtin_amdgcn_s_barrier();
        __builtin_amdgcn_sched_barrier(0);

        if (i + 2 < ntil) STAGE256(i + 2, cur);
        cur ^= 1;
    }
#undef STAGE256
}

// ---------------------------------------------------------------------------
// prior: one WAVE per (b,i) row — no LDS, no barriers, no atomics.
// ---------------------------------------------------------------------------
__device__ __forceinline__ void prior_wave(
    const float* __restrict__ x, const float* __restrict__ wsv,
    float* __restrict__ pout, int row, int lane)
{
    const float4* xr = (const float4*)(x + (size_t)row * 512);
    const float4* wr = (const float4*)wsv;
    float4 a0 = xr[lane * 2],     b0 = wr[lane * 2];
    float4 a1 = xr[lane * 2 + 1], b1 = wr[lane * 2 + 1];
    float part = a0.x * b0.x + a0.y * b0.y + a0.z * b0.z + a0.w * b0.w
               + a1.x * b1.x + a1.y * b1.y + a1.z * b1.z + a1.w * b1.w;
    #pragma unroll
    for (int o = 32; o; o >>= 1) part += __shfl_xor(part, o, 64);
    float sigma = part;
    float inv2 = 0.5f / (sigma * sigma);

    int i = row & 2047;
    float g[32];
    float sum = 0.f;
    #pragma unroll
    for (int u = 0; u < 8; u++) {
        #pragma unroll
        for (int v = 0; v < 4; v++) {
            float d = (float)(u * 256 + lane * 4 + v - i);
            float e = __expf(-(d * d) * inv2);
            g[u * 4 + v] = e;
            sum += e;
        }
    }
    #pragma unroll
    for (int o = 32; o; o >>= 1) sum += __shfl_xor(sum, o, 64);
    float inv = 1.0f / sum;

    float4* pr = (float4*)(pout + (size_t)row * 2048);
    #pragma unroll
    for (int u = 0; u < 8; u++) {
        float4 o4 = { g[u * 4] * inv, g[u * 4 + 1] * inv,
                      g[u * 4 + 2] * inv, g[u * 4 + 3] * inv };
        pr[u * 64 + lane] = o4;
    }
}

// ---------------------------------------------------------------------------
// Kernel 1: convert x -> bf16 row-major; W{q,k,v} -> bf16 transposed [n][k]
// via 64x64 LDS-transpose tiles. Grid 4288. (R6-verified, unchanged.)
// ---------------------------------------------------------------------------
__global__ __launch_bounds__(256) void k_convert(
    const float* __restrict__ x, const float* __restrict__ wq,
    const float* __restrict__ wk, const float* __restrict__ wv,
    unsigned short* __restrict__ xbf, unsigned short* __restrict__ wt)
{
    __shared__ __align__(16) unsigned short lt[64][72];   // 64x64 tile, padded

    int bid = blockIdx.x, t = threadIdx.x;
    if (bid < 4096) {
        int gid = bid * 256 + t;
        float4 v = ((const float4*)x)[gid];
        us4 o = { f2bf(v.x), f2bf(v.y), f2bf(v.z), f2bf(v.w) };
        ((us4*)xbf)[gid] = o;
    } else {
        int idx = bid - 4096;
        int w = idx >> 6;                    // 0=q 1=k 2=v
        int tile = idx & 63;
        int tk = tile >> 3, tn = tile & 7;
        const float* src = ((w == 0) ? wq : (w == 1) ? wk : wv)
                         + (size_t)(tk * 64) * 512 + tn * 64;

        int row = t >> 2;
        int c0 = (t & 3) * 16;
        const float4* s = (const float4*)(src + (size_t)row * 512 + c0);
        #pragma unroll
        for (int q = 0; q < 4; q++) {
            float4 v = s[q];
            lt[c0 + q * 4 + 0][row] = f2bf(v.x);
            lt[c0 + q * 4 + 1][row] = f2bf(v.y);
            lt[c0 + q * 4 + 2][row] = f2bf(v.z);
            lt[c0 + q * 4 + 3][row] = f2bf(v.w);
        }
        __syncthreads();

        int n = t >> 2;
        int k0 = (t & 3) * 16;
        s16x8 a = *(const s16x8*)&lt[n][k0];
        s16x8 b = *(const s16x8*)&lt[n][k0 + 8];
        unsigned short* dst = wt + (((size_t)(w * 512 + tn * 64 + n)) << 9)
                                 + tk * 64 + k0;
        *(s16x8*)dst = a;
        *(s16x8*)(dst + 8) = b;
    }
}

// ---------------------------------------------------------------------------
// Kernel 2: QKV projection. Grid 192, 512 thr. XCD-chunked swizzle (R11,
// verified −14µs total): XCD x owns 4 m-tiles x 6 n-tiles -> L2-resident.
// ---------------------------------------------------------------------------
__global__ __launch_bounds__(512, 2) void k_proj(
    const unsigned short* __restrict__ xbf, const unsigned short* __restrict__ wt,
    unsigned short* __restrict__ qbf, unsigned short* __restrict__ kbf,
    unsigned short* __restrict__ vtbf)
{
    __shared__ __align__(16) unsigned short sh[32768];   // 64KB: 2 x 16384

    int t = threadIdx.x;
    int xcd = blockIdx.x & 7, j = blockIdx.x >> 3;    // j in [0,24)
    int mt_ = xcd * 4 + j / 6, nt_ = j % 6;
    int m0 = mt_ * 256, n0 = nt_ * 256;

    f32x4 acc[8][4] = {};
    gemm_core256(xbf + (size_t)m0 * 512, 512, wt + (size_t)n0 * 512, 512,
                 512, sh, t, acc);

    int w = t >> 6, lane = t & 63, c = lane & 15, quad = lane >> 4;
    int wr = w >> 2, wc = w & 3;
    int sel = nt_ >> 1;                           // 0=q 1=k 2=v

    if (sel < 2) {
        unsigned short* dst = sel ? kbf : qbf;
        int ncol0 = n0 - sel * 512;
        #pragma unroll
        for (int mt = 0; mt < 8; mt++) {
            #pragma unroll
            for (int nt = 0; nt < 4; nt++) {
                int col = ncol0 + wc * 64 + nt * 16 + c;
                #pragma unroll
                for (int r = 0; r < 4; r++) {
                    int rw = m0 + wr * 128 + mt * 16 + quad * 4 + r;
                    dst[(size_t)rw * 512 + col] = f2bf(acc[mt][nt][r]);
                }
            }
        }
    } else {
        #pragma unroll
        for (int mt = 0; mt < 8; mt++) {
            int rw0 = m0 + wr * 128 + mt * 16 + quad * 4;
            int bb = rw0 >> 11, nn = rw0 & 2047;
            #pragma unroll
            for (int nt = 0; nt < 4; nt++) {
                int d = (n0 - 1024) + wc * 64 + nt * 16 + c;
                us4 pk = { f2bf(acc[mt][nt][0]), f2bf(acc[mt][nt][1]),
                           f2bf(acc[mt][nt][2]), f2bf(acc[mt][nt][3]) };
                *(us4*)(vtbf + ((size_t)(bb * 512 + d)) * 2048 + nn) = pk;
            }
        }
    }
}

// ---------------------------------------------------------------------------
// Kernel 3: score. Grid 256, 512 thr. XCD-chunked swizzle (R11-verified):
// XCD x owns (b = x>>1, m-half = x&1) -> Q 1MB + K 2MB in its L2.
// ---------------------------------------------------------------------------
__global__ __launch_bounds__(512, 2) void k_score(
    const unsigned short* __restrict__ qbf, const unsigned short* __restrict__ kbf,
    unsigned short* __restrict__ pbf)
{
    __shared__ __align__(16) unsigned short sh[32768];

    int t = threadIdx.x;
    int xcd = blockIdx.x & 7, j = blockIdx.x >> 3;    // j in [0,32)
    int b = xcd >> 1;
    int m0 = ((xcd & 1) * 4 + (j >> 3)) * 256;
    int n0 = (j & 7) * 256;

    f32x4 acc[8][4] = {};
    gemm_core256(qbf + (size_t)(b * 2048 + m0) * 512, 512,
                 kbf + (size_t)(b * 2048 + n0) * 512, 512,
                 512, sh, t, acc);

    int w = t >> 6, lane = t & 63, c = lane & 15, quad = lane >> 4;
    int wr = w >> 2, wc = w & 3;
    const float scale = 0.044194173824159216f;    // 1/sqrt(512)

    #pragma unroll
    for (int mt = 0; mt < 8; mt++) {
        #pragma unroll
        for (int nt = 0; nt < 4; nt++) {
            int col = n0 + wc * 64 + nt * 16 + c;
            #pragma unroll
            for (int r2 = 0; r2 < 4; r2++) {
                int row = m0 + wr * 128 + mt * 16 + quad * 4 + r2;
                pbf[(size_t)(b * 2048 + row) * 2048 + col]
                    = f2bf(__expf(acc[mt][nt][r2] * scale));
            }
        }
    }
}

// ---------------------------------------------------------------------------
// k_out body: O = P @ Vt^T / l. 128x64 tile, BK=64 via paired BK=32 slabs
// (R10/R11-verified; R12's BK=32 revert was −2.2µs worse, R13's depth-4
// single-barrier worse, R15's setprio worse — this is the best-measured
// form). 48KB LDS, vmcnt(6) steady. l via ones-fragment MFMA.
// ---------------------------------------------------------------------------
__device__ __forceinline__ void out_body(
    const unsigned short* __restrict__ pbf, const unsigned short* __restrict__ vtbf,
    float* __restrict__ zout, int b, int m0, int n0, int t,
    unsigned short* sh)
{
    const int wave = t >> 6, lane = t & 63;
    const int c = lane & 15, quad = lane >> 4;
    const int wm = (wave >> 1) * 64, wn = (wave & 1) * 32;
    const int srow = t >> 2;
    const int scol = (t & 3) * 8;

    const unsigned short* ga = pbf + (size_t)(b * 2048 + m0 + srow) * 2048 + scol;
    const unsigned short* gb = vtbf + (size_t)(b * 512 + n0 + srow) * 2048 + scol;

    s16x8 ones;
    #pragma unroll
    for (int i = 0; i < 8; i++) ones[i] = (short)0x3F80;    // bf16 1.0

    f32x4 acc[4][2] = {};
    f32x4 accl[4] = {};

#define STAGEPAIR(p, bbuf) do {                                     \
        unsigned short* nb = sh + (bbuf) * 12288;                   \
        int kk = (p) * 64;                                          \
        GLOAD_LDS16(ga + kk,             nb + t * 8);               \
        GLOAD_LDS16(ga + kk + 64 * 2048, nb + 2048 + t * 8);        \
        GLOAD_LDS16(gb + kk,             nb + 4096 + t * 8);        \
        GLOAD_LDS16(ga + kk + 32,             nb + 6144 + t * 8);   \
        GLOAD_LDS16(ga + kk + 32 + 64 * 2048, nb + 8192 + t * 8);   \
        GLOAD_LDS16(gb + kk + 32,             nb + 10240 + t * 8);  \
    } while (0)

    STAGEPAIR(0, 0);
    STAGEPAIR(1, 1);

    int cur = 0;
    for (int i = 0; i < 32; i++) {
        if (i + 1 < 32) asm volatile("s_waitcnt vmcnt(6)" ::: "memory");
        else            asm volatile("s_waitcnt vmcnt(0)" ::: "memory");
        __builtin_amdgcn_s_barrier();
        __builtin_amdgcn_sched_barrier(0);

        const unsigned short* buf = sh + cur * 12288;
        s16x8 a0[4], b0[2], a1[4], b1[2];
        #pragma unroll
        for (int q = 0; q < 4; q++)
            a0[q] = *(const s16x8*)(buf + (wm + q * 16 + c) * 32 + quad * 8);
        #pragma unroll
        for (int q = 0; q < 2; q++)
            b0[q] = *(const s16x8*)(buf + 4096 + (wn + q * 16 + c) * 32 + quad * 8);
        #pragma unroll
        for (int q = 0; q < 4; q++)
            a1[q] = *(const s16x8*)(buf + 6144 + (wm + q * 16 + c) * 32 + quad * 8);
        #pragma unroll
        for (int q = 0; q < 2; q++)
            b1[q] = *(const s16x8*)(buf + 10240 + (wn + q * 16 + c) * 32 + quad * 8);

        asm volatile("s_waitcnt lgkmcnt(0)" ::: "memory");
        __builtin_amdgcn_sched_barrier(0);

        #pragma unroll
        for (int mt = 0; mt < 4; mt++) {
            #pragma unroll
            for (int nt = 0; nt < 2; nt++)
                acc[mt][nt] = MFMA16(a0[mt], b0[nt], acc[mt][nt]);
            accl[mt] = MFMA16(a0[mt], ones, accl[mt]);
        }
        #pragma unroll
        for (int mt = 0; mt < 4; mt++) {
            #pragma unroll
            for (int nt = 0; nt < 2; nt++)
                acc[mt][nt] = MFMA16(a1[mt], b1[nt], acc[mt][nt]);
            accl[mt] = MFMA16(a1[mt], ones, accl[mt]);
        }

        __builtin_amdgcn_s_barrier();
        __builtin_amdgcn_sched_barrier(0);

        if (i + 2 < 32) STAGEPAIR(i + 2, cur);
        cur ^= 1;
    }
#undef STAGEPAIR

    #pragma unroll
    for (int mt = 0; mt < 4; mt++) {
        #pragma unroll
        for (int r = 0; r < 4; r++) {
            int row = wm + mt * 16 + quad * 4 + r;
            float inv = 1.0f / accl[mt][r];
            #pragma unroll
            for (int nt = 0; nt < 2; nt++) {
                zout[(size_t)(b * 2048 + m0 + row) * 512 + n0 + wn + nt * 16 + c]
                    = acc[mt][nt][r] * inv;
            }
        }
    }
}

// out block-index decode, XCD-chunked (R11-verified, −14µs): XCD x owns
// groups g in [8x, 8x+8) (group = (b,m) pair sharing one 512KB P-tile);
// n fastest -> the 8 sharers of each P-tile are adjacent on ONE XCD's L2.
__device__ __forceinline__ void out_decode(int bid, int& b, int& m0, int& n0)
{
    int xcd = bid & 7, j = bid >> 3;     // j in [0,64)
    int g = xcd * 8 + (j >> 3);          // group in [0,64)
    b = g >> 4;
    m0 = (g & 15) * 128;
    n0 = (j & 7) * 64;
}

// ---------------------------------------------------------------------------
// Kernel 4a (ws path): output + prior merged. Grid 2560 (256 thr):
// [0,512) out tiles (XCD-chunked decode); [512,2560) prior (4 rows/block).
// ---------------------------------------------------------------------------
__global__ __launch_bounds__(256) void k_out_prior(
    const unsigned short* __restrict__ pbf, const unsigned short* __restrict__ vtbf,
    float* __restrict__ zout,
    const float* __restrict__ x, const float* __restrict__ wsv,
    float* __restrict__ pout)
{
    __shared__ __align__(16) unsigned short sh[24576];   // 48KB: 2 x 12288

    int bid = blockIdx.x, t = threadIdx.x;
    if (bid < 512) {
        int b, m0, n0;
        out_decode(bid, b, m0, n0);
        out_body(pbf, vtbf, zout, b, m0, n0, t, sh);
    } else {
        int row = (bid - 512) * 4 + (t >> 6);
        prior_wave(x, wsv, pout, row, t & 63);
    }
}

// ---------------------------------------------------------------------------
// Kernel 4b (fallback): pure output. Grid 512, 256 thr.
// ---------------------------------------------------------------------------
__global__ __launch_bounds__(256) void k_out(
    const unsigned short* __restrict__ pbf, const unsigned short* __restrict__ vtbf,
    float* __restrict__ zout)
{
    __shared__ __align__(16) unsigned short sh[24576];
    int b, m0, n0;
    out_decode(blockIdx.x, b, m0, n0);
    out_body(pbf, vtbf, zout, b, m0, n0, threadIdx.x, sh);
}

// ---------------------------------------------------------------------------
// Kernel 5 (fallback): standalone prior. Grid 2048, 256 thr, 4 rows/block.
// ---------------------------------------------------------------------------
__global__ __launch_bounds__(256) void k_prior(
    const float* __restrict__ x, const float* __restrict__ wsv,
    float* __restrict__ pout)
{
    int row = blockIdx.x * 4 + (threadIdx.x >> 6);
    prior_wave(x, wsv, pout, row, threadIdx.x & 63);
}

// ---------------------------------------------------------------------------
extern "C" void kernel_launch(void* const* d_in, const int* in_sizes, int n_in,
                              void* d_out, int out_size, void* d_ws, size_t ws_size,
                              hipStream_t stream)
{
    const float* x  = (const float*)d_in[0];
    const float* wq = (const float*)d_in[1];
    const float* wk = (const float*)d_in[2];
    const float* wv = (const float*)d_in[3];
    const float* ws = (const float*)d_in[4];

    float* zout = (float*)d_out;                       // (4,2048,512)
    float* pout = zout + (size_t)4 * 2048 * 512;       // (4,2048,2048) = 67.1 MB

    // Scratch: xbf 4.19M + wt 0.79M + q/k/vt 3*4.19M + pbf 16.78M ushorts.
    const size_t need = ((size_t)4194304 + 786432 + 3 * 4194304 + 16777216) * 2;

    if (ws_size >= need) {
        // ---- ws path: all scratch in d_ws; prior overlaps k_out's compute
        unsigned short* base = (unsigned short*)d_ws;
        unsigned short* xbf  = base;
        unsigned short* wt   = xbf  + (size_t)4194304;
        unsigned short* qbf  = wt   + (size_t)786432;
        unsigned short* kbf  = qbf  + (size_t)4194304;
        unsigned short* vtbf = kbf  + (size_t)4194304;
        unsigned short* pbf  = vtbf + (size_t)4194304;

        k_convert  <<<dim3(4288), dim3(256), 0, stream>>>(x, wq, wk, wv, xbf, wt);
        k_proj     <<<dim3(192),  dim3(512), 0, stream>>>(xbf, wt, qbf, kbf, vtbf);
        k_score    <<<dim3(256),  dim3(512), 0, stream>>>(qbf, kbf, pbf);
        k_out_prior<<<dim3(2560), dim3(256), 0, stream>>>(pbf, vtbf, zout, x, ws, pout);
    } else {
        // ---- fallback: scratch inside pout (prior runs last)
        unsigned short* base = (unsigned short*)pout;
        unsigned short* pbf  = base;                        // 16,777,216
        unsigned short* qbf  = base + (size_t)16777216;
        unsigned short* kbf  = qbf  + (size_t)4194304;
        unsigned short* vtbf = kbf  + (size_t)4194304;
        unsigned short* xbf  = base;                        // overlaps pbf (ok)
        unsigned short* wt   = base + (size_t)4194304;      // overlaps pbf (ok)

        k_convert<<<dim3(4288), dim3(256), 0, stream>>>(x, wq, wk, wv, xbf, wt);
        k_proj   <<<dim3(192),  dim3(512), 0, stream>>>(xbf, wt, qbf, kbf, vtbf);
        k_score  <<<dim3(256),  dim3(512), 0, stream>>>(qbf, kbf, pbf);
        k_out    <<<dim3(512),  dim3(256), 0, stream>>>(pbf, vtbf, zout);
        k_prior  <<<dim3(2048), dim3(256), 0, stream>>>(x, ws, pout);
    }
}